// Round 11
// baseline (85.025 us; speedup 1.0000x reference)
//
#include <hip/hip_runtime.h>
#include <math.h>

// ---------------------------------------------------------------------------
// VQ-VAE eval forward.  N=65536 points x K=1024 codes x D=64, fp32 in/out.
// Distances via f16x2 split-precision MFMA (16x16x32_f16), numerics as R2-R10:
//   z = zh + 2^-12 zl', e = eh + 2^-12 el'  (lo pre-scaled by 4096)
//   argmax key m = (zh.eh - esq/2) + 2^-12 (zh.el' + zl'.eh)
// R11 = R4 (61 us champion: 1024 blk x 256 thr, 4 waves = 2 pt-halves x
// 2 K-halves, 64-code chunks, 2-buf drain-per-phase, verified-conflict-free
// XOR swizzle, launch_bounds(256,4)) + vq_fin FOLDED into vq_main via
// device-scope last-block counter (saves one dispatch + launch gap).
// Cross-XCD coherence per G16: threadfence+atomic counter (release),
// agent-scope atomic loads of hist/lossp in the last block (acquire).
// ---------------------------------------------------------------------------

#define QOUT_SZ  4194304            // 16*64*64*64
#define LOSS_OFF QOUT_SZ
#define IDX_OFF  (QOUT_SZ + 1)
#define PERP_OFF (QOUT_SZ + 1 + 65536)

typedef _Float16 f16x8 __attribute__((ext_vector_type(8)));
typedef _Float16 f16x4 __attribute__((ext_vector_type(4)));
typedef float    f32x4 __attribute__((ext_vector_type(4)));

// ws byte offsets
#define WS_EHI   0          // _Float16[65536] (128 KB)
#define WS_ELO   131072     // _Float16[65536] (128 KB)
#define WS_ESQ   262144     // float[1024]  (stores -0.5*||e||^2)
#define WS_HIST  266240     // float[1024]
#define WS_LOSS  270336     // float[1024]
#define WS_CNT   274432     // int[1]  block-completion counter

__device__ __forceinline__ void gll16(const void* g, void* l) {
    __builtin_amdgcn_global_load_lds(
        (const __attribute__((address_space(1))) void*)g,
        (__attribute__((address_space(3))) void*)l, 16, 0, 0);
}

// ---------------------------------------------------------------------------
// Prep: split-convert embedding, esq[k] = -0.5*||e_k||^2, zero hist + counter.
// ---------------------------------------------------------------------------
__global__ void vq_pre(const float* __restrict__ emb,
                       _Float16* __restrict__ ehi, _Float16* __restrict__ elo,
                       float* __restrict__ esq, float* __restrict__ hist,
                       int* __restrict__ cnt) {
    const int t = threadIdx.x;
    const int g = blockIdx.x * 256 + t;          // float4 unit 0..16383
    float4 v = ((const float4*)emb)[g];
    float xs[4] = {v.x, v.y, v.z, v.w};
    f16x4 hi, lo;
    float ss = 0.f;
#pragma unroll
    for (int j = 0; j < 4; ++j) {
        _Float16 h = (_Float16)xs[j];
        hi[j] = h;
        lo[j] = (_Float16)((xs[j] - (float)h) * 4096.0f);
        ss = fmaf(xs[j], xs[j], ss);
    }
    ((f16x4*)ehi)[g] = hi;
    ((f16x4*)elo)[g] = lo;
    ss += __shfl_xor(ss, 1, 64);
    ss += __shfl_xor(ss, 2, 64);
    ss += __shfl_xor(ss, 4, 64);
    ss += __shfl_xor(ss, 8, 64);
    if ((t & 15) == 0) esq[g >> 4] = -0.5f * ss;
    if (blockIdx.x < 4) hist[blockIdx.x * 256 + t] = 0.f;
    if (blockIdx.x == 0 && t == 0) *cnt = 0;
}

// ---------------------------------------------------------------------------
// Main. 1024 blocks x 256 threads (4 waves). Block owns 64 points (1 bh row).
// Wave (pg,ksel): pg = 32-pt half, ksel = 32-code half of each 64-code chunk.
// 16 chunks of 64 codes, 2-buffered. Last block computes loss + perplexity.
// ---------------------------------------------------------------------------
__launch_bounds__(256, 4)
__global__ void vq_main(const float* __restrict__ z,
                        const float* __restrict__ emb,
                        const _Float16* __restrict__ gehi,
                        const _Float16* __restrict__ gelo,
                        const float* __restrict__ gesq,
                        float* __restrict__ hist,
                        float* __restrict__ lossp,
                        int* __restrict__ cnt,
                        float* __restrict__ out) {
    __shared__ __align__(16) char es[32768];   // 2 bufs x (hi 8K | lo 8K)
    __shared__ float esql[1024];               // -esq/2 (reused as fin scratch)
    __shared__ float candv[128];
    __shared__ int   candi[128];
    __shared__ int   idxs[64];
    __shared__ float redw[4];
    __shared__ int   lastFlag;

    const int tid  = threadIdx.x;
    const int blk  = blockIdx.x;               // = b*64 + h
    const int b    = blk >> 6;
    const int h    = blk & 63;
    const int lane = tid & 63;
    const int wv   = tid >> 6;                 // 0..3
    const int pg   = wv & 1;                   // point half (w 0-31 / 32-63)
    const int ksel = wv >> 1;                  // code half of chunk
    const int col  = lane & 15;
    const int g    = lane >> 4;                // 0..3

    // ---- stage -esq/2 into LDS (coalesced, once) ----
#pragma unroll
    for (int i = 0; i < 4; ++i) esql[tid + 256 * i] = gesq[tid + 256 * i];

    // ---- A fragments straight from global: lane col = point row ----
    const float* zb = z + (size_t)b * 262144 + (size_t)h * 64;
    const float* zrow = zb + pg * 32 + col;
    f16x8 Ah[2][2], Al[2][2];
#pragma unroll
    for (int pt = 0; pt < 2; ++pt) {
#pragma unroll
        for (int m = 0; m < 2; ++m) {
#pragma unroll
            for (int j = 0; j < 8; ++j) {
                int c = m * 32 + g * 8 + j;
                float x = zrow[pt * 16 + (size_t)c * 4096];
                _Float16 hh = (_Float16)x;
                Ah[pt][m][j] = hh;
                Al[pt][m][j] = (_Float16)((x - (float)hh) * 4096.0f);
            }
        }
    }

    // ---- staging geometry (verified conflict-free, R4-R10) ----
    const char* gh = (const char*)gehi;
    const char* gl = (const char*)gelo;
    const int u0 = tid, u1 = tid + 256;
    const int c0 = u0 >> 3, c1 = u1 >> 3;
    const size_t so0 = (size_t)c0 * 128 + (size_t)(((u0 & 7) ^ (c0 & 7)) * 16);
    const size_t so1 = (size_t)c1 * 128 + (size_t)(((u1 & 7) ^ (c1 & 7)) * 16);
    char* const dA = es + wv * 1024;           // wave-uniform dest base

#define STAGE(n, bb) do { \
        const size_t gb_ = (size_t)(n) * 8192; \
        char* d_ = dA + (bb) * 16384; \
        gll16(gh + gb_ + so0, d_);            \
        gll16(gh + gb_ + so1, d_ + 4096);     \
        gll16(gl + gb_ + so0, d_ + 8192);     \
        gll16(gl + gb_ + so1, d_ + 12288);    \
    } while (0)

    // ---- per-lane B read offsets (swizzled, loop-invariant) ----
    int rb[2][2];
#pragma unroll
    for (int ct = 0; ct < 2; ++ct) {
        int cl = ksel * 32 + ct * 16 + col;
#pragma unroll
        for (int m = 0; m < 2; ++m)
            rb[ct][m] = cl * 128 + ((((m * 4 + g) * 16)) ^ ((col & 7) << 4));
    }

    float best[2][4];
    int   besti[2][4];
#pragma unroll
    for (int pt = 0; pt < 2; ++pt)
#pragma unroll
        for (int r = 0; r < 4; ++r) { best[pt][r] = -3.4e38f; besti[pt][r] = 0; }

    STAGE(0, 0);

    // ---- k loop: 16 chunks of 64 codes (each wave uses its 32) ----
    for (int sc = 0; sc < 16; ++sc) {
        const int cur = sc & 1;
        asm volatile("s_waitcnt vmcnt(0)" ::: "memory");
        __builtin_amdgcn_s_barrier();
        asm volatile("" ::: "memory");
        if (sc < 15) STAGE(sc + 1, cur ^ 1);

        const char* bp = es + cur * 16384;
        const int kb = sc * 64 + ksel * 32;
#pragma unroll
        for (int ct = 0; ct < 2; ++ct) {
            const float e2  = esql[kb + ct * 16 + col];
            const int  kidx = kb + ct * 16 + col;
            f16x8 Bh0 = *(const f16x8*)(bp + rb[ct][0]);
            f16x8 Bh1 = *(const f16x8*)(bp + rb[ct][1]);
            f16x8 Bl0 = *(const f16x8*)(bp + 8192 + rb[ct][0]);
            f16x8 Bl1 = *(const f16x8*)(bp + 8192 + rb[ct][1]);
#pragma unroll
            for (int pt = 0; pt < 2; ++pt) {
                f32x4 ah = {e2, e2, e2, e2};
                f32x4 ax = {0.f, 0.f, 0.f, 0.f};
                ah = __builtin_amdgcn_mfma_f32_16x16x32_f16(Ah[pt][0], Bh0, ah, 0, 0, 0);
                ah = __builtin_amdgcn_mfma_f32_16x16x32_f16(Ah[pt][1], Bh1, ah, 0, 0, 0);
                ax = __builtin_amdgcn_mfma_f32_16x16x32_f16(Ah[pt][0], Bl0, ax, 0, 0, 0);
                ax = __builtin_amdgcn_mfma_f32_16x16x32_f16(Ah[pt][1], Bl1, ax, 0, 0, 0);
                ax = __builtin_amdgcn_mfma_f32_16x16x32_f16(Al[pt][0], Bh0, ax, 0, 0, 0);
                ax = __builtin_amdgcn_mfma_f32_16x16x32_f16(Al[pt][1], Bh1, ax, 0, 0, 0);
#pragma unroll
                for (int r = 0; r < 4; ++r) {
                    float mval = fmaf(0x1p-12f, ax[r], ah[r]);
                    if (mval > best[pt][r]) { best[pt][r] = mval; besti[pt][r] = kidx; }
                }
            }
        }
    }
#undef STAGE

    // ---- in-wave argmin over the 16 code-cols (butterfly, np tie-break) ----
#pragma unroll
    for (int mask = 1; mask <= 8; mask <<= 1) {
#pragma unroll
        for (int pt = 0; pt < 2; ++pt)
#pragma unroll
            for (int r = 0; r < 4; ++r) {
                float ov = __shfl_xor(best[pt][r], mask, 64);
                int   oi = __shfl_xor(besti[pt][r], mask, 64);
                if (ov > best[pt][r] ||
                    (ov == best[pt][r] && oi < besti[pt][r])) {
                    best[pt][r] = ov; besti[pt][r] = oi;
                }
            }
    }
    if (col == 0) {
#pragma unroll
        for (int pt = 0; pt < 2; ++pt)
#pragma unroll
            for (int r = 0; r < 4; ++r) {
                int p = pg * 32 + pt * 16 + g * 4 + r;
                candv[p * 2 + ksel] = best[pt][r];
                candi[p * 2 + ksel] = besti[pt][r];
            }
    }
    __syncthreads();

    // ---- combine the two K-halves, write idx, histogram ----
    if (tid < 64) {
        float v0 = candv[tid * 2],     v1 = candv[tid * 2 + 1];
        int   i0 = candi[tid * 2],     i1 = candi[tid * 2 + 1];
        int bi = (v1 > v0 || (v1 == v0 && i1 < i0)) ? i1 : i0;
        idxs[tid] = bi;
        atomicAdd(&hist[bi], 1.0f);               // exact int counts
        out[(size_t)IDX_OFF + blk * 64 + tid] = (float)bi;
    }
    __syncthreads();

    // ---- epilogue: quantized write (coalesced over w) + loss partial ----
    const int w  = tid & 63;
    const int cq = tid >> 6;                      // channels cq*16..cq*16+15
    const int idx = idxs[w];
    const float* ev = emb + (size_t)idx * 64 + cq * 16;
    const float* zr = zb + w;
    float* outq = out + (size_t)b * 262144 + (size_t)h * 64 + w;
    float lsum = 0.f;
#pragma unroll
    for (int i = 0; i < 4; ++i) {
        float4 qv = *(const float4*)(ev + i * 4);
        float q4[4] = {qv.x, qv.y, qv.z, qv.w};
#pragma unroll
        for (int jj = 0; jj < 4; ++jj) {
            int c = cq * 16 + i * 4 + jj;
            float zv = zr[(size_t)c * 4096];      // L3-hot re-read
            outq[(size_t)c * 4096] = q4[jj];
            float d = q4[jj] - zv;
            lsum = fmaf(d, d, lsum);
        }
    }
#pragma unroll
    for (int off = 32; off > 0; off >>= 1)
        lsum += __shfl_xor(lsum, off, 64);
    if (lane == 0) redw[wv] = lsum;
    __syncthreads();

    // ---- signal completion (release) ----
    if (tid == 0) {
        float s = redw[0] + redw[1] + redw[2] + redw[3];
        __hip_atomic_store(&lossp[blk], s, __ATOMIC_RELAXED,
                           __HIP_MEMORY_SCOPE_AGENT);
        __threadfence();
        int prev = atomicAdd(cnt, 1);
        lastFlag = (prev == 1023);
    }
    __syncthreads();

    // ---- last block: loss + perplexity (acquire via agent-scope loads) ----
    if (lastFlag) {
        __threadfence();
        float hs = 0.f, ls = 0.f;
#pragma unroll
        for (int i = 0; i < 4; ++i) {
            float hc = __hip_atomic_load(&hist[tid + 256 * i],
                                         __ATOMIC_RELAXED,
                                         __HIP_MEMORY_SCOPE_AGENT);
            float p = hc * (1.0f / 65536.0f);
            hs += p * logf(p + 1e-10f);
            ls += __hip_atomic_load(&lossp[tid + 256 * i],
                                    __ATOMIC_RELAXED,
                                    __HIP_MEMORY_SCOPE_AGENT);
        }
        esql[tid] = hs;
        esql[256 + tid] = ls;
        __syncthreads();
        for (int s = 128; s > 0; s >>= 1) {
            if (tid < s) {
                esql[tid] += esql[tid + s];
                esql[256 + tid] += esql[256 + tid + s];
            }
            __syncthreads();
        }
        if (tid == 0) {
            out[LOSS_OFF] = 0.25f * esql[256] / (float)QOUT_SZ;
            out[PERP_OFF] = expf(-esql[0]);
        }
    }
}

extern "C" void kernel_launch(void* const* d_in, const int* in_sizes, int n_in,
                              void* d_out, int out_size, void* d_ws, size_t ws_size,
                              hipStream_t stream) {
    const float* z   = (const float*)d_in[0];   // [16,64,64,64] fp32 NCHW
    const float* emb = (const float*)d_in[1];   // [1024,64] fp32
    float* out = (float*)d_out;
    char*  ws  = (char*)d_ws;

    _Float16* ehi   = (_Float16*)(ws + WS_EHI);
    _Float16* elo   = (_Float16*)(ws + WS_ELO);
    float*    esq   = (float*)(ws + WS_ESQ);
    float*    hist  = (float*)(ws + WS_HIST);
    float*    lossp = (float*)(ws + WS_LOSS);
    int*      cnt   = (int*)(ws + WS_CNT);

    vq_pre<<<64, 256, 0, stream>>>(emb, ehi, elo, esq, hist, cnt);
    vq_main<<<1024, 256, 0, stream>>>(z, emb, ehi, elo, esq, hist, lossp, cnt, out);
}

// Round 12
// 83.809 us; speedup vs baseline: 1.0145x; 1.0145x over previous
//
#include <hip/hip_runtime.h>
#include <math.h>

// ---------------------------------------------------------------------------
// VQ-VAE eval forward.  N=65536 points x K=1024 codes x D=64, fp32 in/out.
// Distances via f16x2 split-precision MFMA (16x16x32_f16), numerics as R2-R11:
//   z = zh + 2^-12 zl', e = eh + 2^-12 el'  (lo pre-scaled by 4096)
//   argmax key m = (zh.eh - esq/2) + 2^-12 (zh.el' + zl'.eh)
// R12 = R11 (R4 hot loop + folded finalize) MINUS __threadfence: the fence
// compiled to a per-block L2 writeback (cross-XCD visibility) costing ~20 us.
// All data read by the last block is written via atomics (device coherence
// point); __syncthreads drains them (vmcnt0 at barrier); ordering needs only
// RELEASE on the counter RMW (pairs with the last incrementer's acquire).
// ---------------------------------------------------------------------------

#define QOUT_SZ  4194304            // 16*64*64*64
#define LOSS_OFF QOUT_SZ
#define IDX_OFF  (QOUT_SZ + 1)
#define PERP_OFF (QOUT_SZ + 1 + 65536)

typedef _Float16 f16x8 __attribute__((ext_vector_type(8)));
typedef _Float16 f16x4 __attribute__((ext_vector_type(4)));
typedef float    f32x4 __attribute__((ext_vector_type(4)));

// ws byte offsets
#define WS_EHI   0          // _Float16[65536] (128 KB)
#define WS_ELO   131072     // _Float16[65536] (128 KB)
#define WS_ESQ   262144     // float[1024]  (stores -0.5*||e||^2)
#define WS_HIST  266240     // float[1024]
#define WS_LOSS  270336     // float[1024]
#define WS_CNT   274432     // int[1]  block-completion counter

__device__ __forceinline__ void gll16(const void* g, void* l) {
    __builtin_amdgcn_global_load_lds(
        (const __attribute__((address_space(1))) void*)g,
        (__attribute__((address_space(3))) void*)l, 16, 0, 0);
}

// ---------------------------------------------------------------------------
// Prep: split-convert embedding, esq[k] = -0.5*||e_k||^2, zero hist + counter.
// ---------------------------------------------------------------------------
__global__ void vq_pre(const float* __restrict__ emb,
                       _Float16* __restrict__ ehi, _Float16* __restrict__ elo,
                       float* __restrict__ esq, float* __restrict__ hist,
                       int* __restrict__ cnt) {
    const int t = threadIdx.x;
    const int g = blockIdx.x * 256 + t;          // float4 unit 0..16383
    float4 v = ((const float4*)emb)[g];
    float xs[4] = {v.x, v.y, v.z, v.w};
    f16x4 hi, lo;
    float ss = 0.f;
#pragma unroll
    for (int j = 0; j < 4; ++j) {
        _Float16 h = (_Float16)xs[j];
        hi[j] = h;
        lo[j] = (_Float16)((xs[j] - (float)h) * 4096.0f);
        ss = fmaf(xs[j], xs[j], ss);
    }
    ((f16x4*)ehi)[g] = hi;
    ((f16x4*)elo)[g] = lo;
    ss += __shfl_xor(ss, 1, 64);
    ss += __shfl_xor(ss, 2, 64);
    ss += __shfl_xor(ss, 4, 64);
    ss += __shfl_xor(ss, 8, 64);
    if ((t & 15) == 0) esq[g >> 4] = -0.5f * ss;
    if (blockIdx.x < 4) hist[blockIdx.x * 256 + t] = 0.f;
    if (blockIdx.x == 0 && t == 0) *cnt = 0;
}

// ---------------------------------------------------------------------------
// Main. 1024 blocks x 256 threads (4 waves). Block owns 64 points (1 bh row).
// Wave (pg,ksel): pg = 32-pt half, ksel = 32-code half of each 64-code chunk.
// 16 chunks of 64 codes, 2-buffered. Last block computes loss + perplexity.
// ---------------------------------------------------------------------------
__launch_bounds__(256, 4)
__global__ void vq_main(const float* __restrict__ z,
                        const float* __restrict__ emb,
                        const _Float16* __restrict__ gehi,
                        const _Float16* __restrict__ gelo,
                        const float* __restrict__ gesq,
                        float* __restrict__ hist,
                        float* __restrict__ lossp,
                        int* __restrict__ cnt,
                        float* __restrict__ out) {
    __shared__ __align__(16) char es[32768];   // 2 bufs x (hi 8K | lo 8K)
    __shared__ float esql[1024];               // -esq/2 (reused as fin scratch)
    __shared__ float candv[128];
    __shared__ int   candi[128];
    __shared__ int   idxs[64];
    __shared__ float redw[4];
    __shared__ int   lastFlag;

    const int tid  = threadIdx.x;
    const int blk  = blockIdx.x;               // = b*64 + h
    const int b    = blk >> 6;
    const int h    = blk & 63;
    const int lane = tid & 63;
    const int wv   = tid >> 6;                 // 0..3
    const int pg   = wv & 1;                   // point half (w 0-31 / 32-63)
    const int ksel = wv >> 1;                  // code half of chunk
    const int col  = lane & 15;
    const int g    = lane >> 4;                // 0..3

    // ---- stage -esq/2 into LDS (coalesced, once) ----
#pragma unroll
    for (int i = 0; i < 4; ++i) esql[tid + 256 * i] = gesq[tid + 256 * i];

    // ---- A fragments straight from global: lane col = point row ----
    const float* zb = z + (size_t)b * 262144 + (size_t)h * 64;
    const float* zrow = zb + pg * 32 + col;
    f16x8 Ah[2][2], Al[2][2];
#pragma unroll
    for (int pt = 0; pt < 2; ++pt) {
#pragma unroll
        for (int m = 0; m < 2; ++m) {
#pragma unroll
            for (int j = 0; j < 8; ++j) {
                int c = m * 32 + g * 8 + j;
                float x = zrow[pt * 16 + (size_t)c * 4096];
                _Float16 hh = (_Float16)x;
                Ah[pt][m][j] = hh;
                Al[pt][m][j] = (_Float16)((x - (float)hh) * 4096.0f);
            }
        }
    }

    // ---- staging geometry (verified conflict-free, R4-R11) ----
    const char* gh = (const char*)gehi;
    const char* gl = (const char*)gelo;
    const int u0 = tid, u1 = tid + 256;
    const int c0 = u0 >> 3, c1 = u1 >> 3;
    const size_t so0 = (size_t)c0 * 128 + (size_t)(((u0 & 7) ^ (c0 & 7)) * 16);
    const size_t so1 = (size_t)c1 * 128 + (size_t)(((u1 & 7) ^ (c1 & 7)) * 16);
    char* const dA = es + wv * 1024;           // wave-uniform dest base

#define STAGE(n, bb) do { \
        const size_t gb_ = (size_t)(n) * 8192; \
        char* d_ = dA + (bb) * 16384; \
        gll16(gh + gb_ + so0, d_);            \
        gll16(gh + gb_ + so1, d_ + 4096);     \
        gll16(gl + gb_ + so0, d_ + 8192);     \
        gll16(gl + gb_ + so1, d_ + 12288);    \
    } while (0)

    // ---- per-lane B read offsets (swizzled, loop-invariant) ----
    int rb[2][2];
#pragma unroll
    for (int ct = 0; ct < 2; ++ct) {
        int cl = ksel * 32 + ct * 16 + col;
#pragma unroll
        for (int m = 0; m < 2; ++m)
            rb[ct][m] = cl * 128 + ((((m * 4 + g) * 16)) ^ ((col & 7) << 4));
    }

    float best[2][4];
    int   besti[2][4];
#pragma unroll
    for (int pt = 0; pt < 2; ++pt)
#pragma unroll
        for (int r = 0; r < 4; ++r) { best[pt][r] = -3.4e38f; besti[pt][r] = 0; }

    STAGE(0, 0);

    // ---- k loop: 16 chunks of 64 codes (each wave uses its 32) ----
    for (int sc = 0; sc < 16; ++sc) {
        const int cur = sc & 1;
        asm volatile("s_waitcnt vmcnt(0)" ::: "memory");
        __builtin_amdgcn_s_barrier();
        asm volatile("" ::: "memory");
        if (sc < 15) STAGE(sc + 1, cur ^ 1);

        const char* bp = es + cur * 16384;
        const int kb = sc * 64 + ksel * 32;
#pragma unroll
        for (int ct = 0; ct < 2; ++ct) {
            const float e2  = esql[kb + ct * 16 + col];
            const int  kidx = kb + ct * 16 + col;
            f16x8 Bh0 = *(const f16x8*)(bp + rb[ct][0]);
            f16x8 Bh1 = *(const f16x8*)(bp + rb[ct][1]);
            f16x8 Bl0 = *(const f16x8*)(bp + 8192 + rb[ct][0]);
            f16x8 Bl1 = *(const f16x8*)(bp + 8192 + rb[ct][1]);
#pragma unroll
            for (int pt = 0; pt < 2; ++pt) {
                f32x4 ah = {e2, e2, e2, e2};
                f32x4 ax = {0.f, 0.f, 0.f, 0.f};
                ah = __builtin_amdgcn_mfma_f32_16x16x32_f16(Ah[pt][0], Bh0, ah, 0, 0, 0);
                ah = __builtin_amdgcn_mfma_f32_16x16x32_f16(Ah[pt][1], Bh1, ah, 0, 0, 0);
                ax = __builtin_amdgcn_mfma_f32_16x16x32_f16(Ah[pt][0], Bl0, ax, 0, 0, 0);
                ax = __builtin_amdgcn_mfma_f32_16x16x32_f16(Ah[pt][1], Bl1, ax, 0, 0, 0);
                ax = __builtin_amdgcn_mfma_f32_16x16x32_f16(Al[pt][0], Bh0, ax, 0, 0, 0);
                ax = __builtin_amdgcn_mfma_f32_16x16x32_f16(Al[pt][1], Bh1, ax, 0, 0, 0);
#pragma unroll
                for (int r = 0; r < 4; ++r) {
                    float mval = fmaf(0x1p-12f, ax[r], ah[r]);
                    if (mval > best[pt][r]) { best[pt][r] = mval; besti[pt][r] = kidx; }
                }
            }
        }
    }
#undef STAGE

    // ---- in-wave argmin over the 16 code-cols (butterfly, np tie-break) ----
#pragma unroll
    for (int mask = 1; mask <= 8; mask <<= 1) {
#pragma unroll
        for (int pt = 0; pt < 2; ++pt)
#pragma unroll
            for (int r = 0; r < 4; ++r) {
                float ov = __shfl_xor(best[pt][r], mask, 64);
                int   oi = __shfl_xor(besti[pt][r], mask, 64);
                if (ov > best[pt][r] ||
                    (ov == best[pt][r] && oi < besti[pt][r])) {
                    best[pt][r] = ov; besti[pt][r] = oi;
                }
            }
    }
    if (col == 0) {
#pragma unroll
        for (int pt = 0; pt < 2; ++pt)
#pragma unroll
            for (int r = 0; r < 4; ++r) {
                int p = pg * 32 + pt * 16 + g * 4 + r;
                candv[p * 2 + ksel] = best[pt][r];
                candi[p * 2 + ksel] = besti[pt][r];
            }
    }
    __syncthreads();

    // ---- combine the two K-halves, write idx, histogram ----
    if (tid < 64) {
        float v0 = candv[tid * 2],     v1 = candv[tid * 2 + 1];
        int   i0 = candi[tid * 2],     i1 = candi[tid * 2 + 1];
        int bi = (v1 > v0 || (v1 == v0 && i1 < i0)) ? i1 : i0;
        idxs[tid] = bi;
        atomicAdd(&hist[bi], 1.0f);               // device-scope atomic
        out[(size_t)IDX_OFF + blk * 64 + tid] = (float)bi;
    }
    __syncthreads();

    // ---- epilogue: quantized write (coalesced over w) + loss partial ----
    const int w  = tid & 63;
    const int cq = tid >> 6;                      // channels cq*16..cq*16+15
    const int idx = idxs[w];
    const float* ev = emb + (size_t)idx * 64 + cq * 16;
    const float* zr = zb + w;
    float* outq = out + (size_t)b * 262144 + (size_t)h * 64 + w;
    float lsum = 0.f;
#pragma unroll
    for (int i = 0; i < 4; ++i) {
        float4 qv = *(const float4*)(ev + i * 4);
        float q4[4] = {qv.x, qv.y, qv.z, qv.w};
#pragma unroll
        for (int jj = 0; jj < 4; ++jj) {
            int c = cq * 16 + i * 4 + jj;
            float zv = zr[(size_t)c * 4096];      // L3-hot re-read
            outq[(size_t)c * 4096] = q4[jj];
            float d = q4[jj] - zv;
            lsum = fmaf(d, d, lsum);
        }
    }
#pragma unroll
    for (int off = 32; off > 0; off >>= 1)
        lsum += __shfl_xor(lsum, off, 64);
    if (lane == 0) redw[wv] = lsum;
    __syncthreads();                              // drains block's atomics too

    // ---- signal completion: RELEASE on the counter RMW (no threadfence) ----
    if (tid == 0) {
        float s = redw[0] + redw[1] + redw[2] + redw[3];
        __hip_atomic_store(&lossp[blk], s, __ATOMIC_RELAXED,
                           __HIP_MEMORY_SCOPE_AGENT);
        int prev = __hip_atomic_fetch_add(cnt, 1, __ATOMIC_ACQ_REL,
                                          __HIP_MEMORY_SCOPE_AGENT);
        lastFlag = (prev == 1023);
    }
    __syncthreads();

    // ---- last block: loss + perplexity via agent-scope atomic loads ----
    if (lastFlag) {
        float hs = 0.f, ls = 0.f;
#pragma unroll
        for (int i = 0; i < 4; ++i) {
            float hc = __hip_atomic_load(&hist[tid + 256 * i],
                                         __ATOMIC_RELAXED,
                                         __HIP_MEMORY_SCOPE_AGENT);
            float p = hc * (1.0f / 65536.0f);
            hs += p * logf(p + 1e-10f);
            ls += __hip_atomic_load(&lossp[tid + 256 * i],
                                    __ATOMIC_RELAXED,
                                    __HIP_MEMORY_SCOPE_AGENT);
        }
        esql[tid] = hs;
        esql[256 + tid] = ls;
        __syncthreads();
        for (int s = 128; s > 0; s >>= 1) {
            if (tid < s) {
                esql[tid] += esql[tid + s];
                esql[256 + tid] += esql[256 + tid + s];
            }
            __syncthreads();
        }
        if (tid == 0) {
            out[LOSS_OFF] = 0.25f * esql[256] / (float)QOUT_SZ;
            out[PERP_OFF] = expf(-esql[0]);
        }
    }
}

extern "C" void kernel_launch(void* const* d_in, const int* in_sizes, int n_in,
                              void* d_out, int out_size, void* d_ws, size_t ws_size,
                              hipStream_t stream) {
    const float* z   = (const float*)d_in[0];   // [16,64,64,64] fp32 NCHW
    const float* emb = (const float*)d_in[1];   // [1024,64] fp32
    float* out = (float*)d_out;
    char*  ws  = (char*)d_ws;

    _Float16* ehi   = (_Float16*)(ws + WS_EHI);
    _Float16* elo   = (_Float16*)(ws + WS_ELO);
    float*    esq   = (float*)(ws + WS_ESQ);
    float*    hist  = (float*)(ws + WS_HIST);
    float*    lossp = (float*)(ws + WS_LOSS);
    int*      cnt   = (int*)(ws + WS_CNT);

    vq_pre<<<64, 256, 0, stream>>>(emb, ehi, elo, esq, hist, cnt);
    vq_main<<<1024, 256, 0, stream>>>(z, emb, ehi, elo, esq, hist, lossp, cnt, out);
}

// Round 13
// 67.461 us; speedup vs baseline: 1.2604x; 1.2423x over previous
//
#include <hip/hip_runtime.h>
#include <math.h>

// ---------------------------------------------------------------------------
// VQ-VAE eval forward.  N=65536 points x K=1024 codes x D=64, fp32 in/out.
// Distances via f16x2 split-precision MFMA (16x16x32_f16), numerics as R2:
//   z = zh + 2^-12 zl', e = eh + 2^-12 el'  (lo pre-scaled by 4096)
//   argmax key m = (zh.eh - esq/2) + 2^-12 (zh.el' + zl'.eh)
// R13 = R4 verbatim (the 61 us champion). Fold experiments (R11/R12) both
// cost +20 us (cross-XCD sync / codegen perturbation) -> 3-kernel structure
// restored. Eight structures mapped R2-R12; all land 61-96 us at MfmaUtil
// 12-16% -> issue-latency plateau at this workload's N/CU occupancy limit.
// ---------------------------------------------------------------------------

#define QOUT_SZ  4194304            // 16*64*64*64
#define LOSS_OFF QOUT_SZ
#define IDX_OFF  (QOUT_SZ + 1)
#define PERP_OFF (QOUT_SZ + 1 + 65536)

typedef _Float16 f16x8 __attribute__((ext_vector_type(8)));
typedef _Float16 f16x4 __attribute__((ext_vector_type(4)));
typedef float    f32x4 __attribute__((ext_vector_type(4)));

// ws byte offsets
#define WS_EHI   0          // _Float16[65536] (128 KB)
#define WS_ELO   131072     // _Float16[65536] (128 KB)
#define WS_ESQ   262144     // float[1024]  (stores -0.5*||e||^2)
#define WS_HIST  266240     // float[1024]
#define WS_LOSS  270336     // float[1024]

__device__ __forceinline__ void gll16(const void* g, void* l) {
    __builtin_amdgcn_global_load_lds(
        (const __attribute__((address_space(1))) void*)g,
        (__attribute__((address_space(3))) void*)l, 16, 0, 0);
}

// ---------------------------------------------------------------------------
// Prep: split-convert embedding, esq[k] = -0.5*||e_k||^2, zero hist. 64 x 256.
// ---------------------------------------------------------------------------
__global__ void vq_pre(const float* __restrict__ emb,
                       _Float16* __restrict__ ehi, _Float16* __restrict__ elo,
                       float* __restrict__ esq, float* __restrict__ hist) {
    const int t = threadIdx.x;
    const int g = blockIdx.x * 256 + t;          // float4 unit 0..16383
    float4 v = ((const float4*)emb)[g];
    float xs[4] = {v.x, v.y, v.z, v.w};
    f16x4 hi, lo;
    float ss = 0.f;
#pragma unroll
    for (int j = 0; j < 4; ++j) {
        _Float16 h = (_Float16)xs[j];
        hi[j] = h;
        lo[j] = (_Float16)((xs[j] - (float)h) * 4096.0f);
        ss = fmaf(xs[j], xs[j], ss);
    }
    ((f16x4*)ehi)[g] = hi;
    ((f16x4*)elo)[g] = lo;
    ss += __shfl_xor(ss, 1, 64);
    ss += __shfl_xor(ss, 2, 64);
    ss += __shfl_xor(ss, 4, 64);
    ss += __shfl_xor(ss, 8, 64);
    if ((t & 15) == 0) esq[g >> 4] = -0.5f * ss;
    if (blockIdx.x < 4) hist[blockIdx.x * 256 + t] = 0.f;
}

// ---------------------------------------------------------------------------
// Main distance/argmin/epilogue kernel. 1024 blocks x 256 threads.
// Block owns 64 points (one (b,h) row). Wave (pg,ksel): pg = 32-pt half,
// ksel = 32-code half of each 64-code superchunk. 16 superchunks, dbuf'd.
// ---------------------------------------------------------------------------
__launch_bounds__(256, 4)
__global__ void vq_main(const float* __restrict__ z,
                        const float* __restrict__ emb,
                        const _Float16* __restrict__ gehi,
                        const _Float16* __restrict__ gelo,
                        const float* __restrict__ gesq,
                        float* __restrict__ hist,
                        float* __restrict__ lossp,
                        float* __restrict__ out) {
    __shared__ __align__(16) char es[32768];   // 2 bufs x (hi 8K | lo 8K)
    __shared__ float esql[1024];               // -esq/2
    __shared__ float candv[128];
    __shared__ int   candi[128];
    __shared__ int   idxs[64];
    __shared__ float redw[4];

    const int tid  = threadIdx.x;
    const int blk  = blockIdx.x;               // = b*64 + h
    const int b    = blk >> 6;
    const int h    = blk & 63;
    const int lane = tid & 63;
    const int wv   = tid >> 6;                 // 0..3
    const int pg   = wv & 1;                   // point half (w 0-31 / 32-63)
    const int ksel = wv >> 1;                  // code half of chunk
    const int col  = lane & 15;
    const int g    = lane >> 4;                // 0..3

    // ---- stage -esq/2 into LDS (coalesced, once) ----
#pragma unroll
    for (int i = 0; i < 4; ++i) esql[tid + 256 * i] = gesq[tid + 256 * i];

    // ---- A fragments straight from global: lane = point row (col) ----
    const float* zb = z + (size_t)b * 262144 + (size_t)h * 64;
    const float* zrow = zb + pg * 32 + col;
    f16x8 Ah[2][2], Al[2][2];
#pragma unroll
    for (int pt = 0; pt < 2; ++pt) {
#pragma unroll
        for (int m = 0; m < 2; ++m) {
#pragma unroll
            for (int j = 0; j < 8; ++j) {
                int c = m * 32 + g * 8 + j;
                float x = zrow[pt * 16 + (size_t)c * 4096];
                _Float16 hh = (_Float16)x;
                Ah[pt][m][j] = hh;
                Al[pt][m][j] = (_Float16)((x - (float)hh) * 4096.0f);
            }
        }
    }

    // ---- staging geometry: superchunk = 64 codes x 128 B per plane ----
    // LDS dest linear in unit u; global source pre-XOR-swizzled (involution).
    const char* gh = (const char*)gehi;
    const char* gl = (const char*)gelo;
    const int u0 = tid, u1 = tid + 256;
    const int c0 = u0 >> 3, c1 = u1 >> 3;
    const size_t so0 = (size_t)c0 * 128 + (size_t)(((u0 & 7) ^ (c0 & 7)) * 16);
    const size_t so1 = (size_t)c1 * 128 + (size_t)(((u1 & 7) ^ (c1 & 7)) * 16);
    char* const dA = es + wv * 1024;           // wave-uniform dest base

#define STAGE(n, bb) do { \
        const size_t gb_ = (size_t)(n) * 8192; \
        char* d_ = dA + (bb) * 16384; \
        gll16(gh + gb_ + so0, d_);            \
        gll16(gh + gb_ + so1, d_ + 4096);     \
        gll16(gl + gb_ + so0, d_ + 8192);     \
        gll16(gl + gb_ + so1, d_ + 12288);    \
    } while (0)

    // ---- per-lane B read offsets (swizzled, loop-invariant) ----
    int rb[2][2];
#pragma unroll
    for (int ct = 0; ct < 2; ++ct) {
        int cl = ksel * 32 + ct * 16 + col;
#pragma unroll
        for (int m = 0; m < 2; ++m)
            rb[ct][m] = cl * 128 + ((((m * 4 + g) * 16)) ^ ((col & 7) << 4));
    }

    float best[2][4];
    int   besti[2][4];
#pragma unroll
    for (int pt = 0; pt < 2; ++pt)
#pragma unroll
        for (int r = 0; r < 4; ++r) { best[pt][r] = -3.4e38f; besti[pt][r] = 0; }

    STAGE(0, 0);

    // ---- k loop: 16 superchunks of 64 codes (each wave uses its 32) ----
    for (int sc = 0; sc < 16; ++sc) {
        const int cur = sc & 1;
        asm volatile("s_waitcnt vmcnt(0)" ::: "memory");
        __builtin_amdgcn_s_barrier();
        asm volatile("" ::: "memory");
        if (sc < 15) STAGE(sc + 1, cur ^ 1);

        const char* bp = es + cur * 16384;
        const int kb = sc * 64 + ksel * 32;
#pragma unroll
        for (int ct = 0; ct < 2; ++ct) {
            const float e2  = esql[kb + ct * 16 + col];
            const int  kidx = kb + ct * 16 + col;
            f16x8 Bh0 = *(const f16x8*)(bp + rb[ct][0]);
            f16x8 Bh1 = *(const f16x8*)(bp + rb[ct][1]);
            f16x8 Bl0 = *(const f16x8*)(bp + 8192 + rb[ct][0]);
            f16x8 Bl1 = *(const f16x8*)(bp + 8192 + rb[ct][1]);
#pragma unroll
            for (int pt = 0; pt < 2; ++pt) {
                f32x4 ah = {e2, e2, e2, e2};
                f32x4 ax = {0.f, 0.f, 0.f, 0.f};
                ah = __builtin_amdgcn_mfma_f32_16x16x32_f16(Ah[pt][0], Bh0, ah, 0, 0, 0);
                ah = __builtin_amdgcn_mfma_f32_16x16x32_f16(Ah[pt][1], Bh1, ah, 0, 0, 0);
                ax = __builtin_amdgcn_mfma_f32_16x16x32_f16(Ah[pt][0], Bl0, ax, 0, 0, 0);
                ax = __builtin_amdgcn_mfma_f32_16x16x32_f16(Ah[pt][1], Bl1, ax, 0, 0, 0);
                ax = __builtin_amdgcn_mfma_f32_16x16x32_f16(Al[pt][0], Bh0, ax, 0, 0, 0);
                ax = __builtin_amdgcn_mfma_f32_16x16x32_f16(Al[pt][1], Bh1, ax, 0, 0, 0);
#pragma unroll
                for (int r = 0; r < 4; ++r) {
                    float mval = fmaf(0x1p-12f, ax[r], ah[r]);
                    if (mval > best[pt][r]) { best[pt][r] = mval; besti[pt][r] = kidx; }
                }
            }
        }
    }
#undef STAGE

    // ---- in-wave argmin over the 16 code-cols (butterfly, np tie-break) ----
#pragma unroll
    for (int mask = 1; mask <= 8; mask <<= 1) {
#pragma unroll
        for (int pt = 0; pt < 2; ++pt)
#pragma unroll
            for (int r = 0; r < 4; ++r) {
                float ov = __shfl_xor(best[pt][r], mask, 64);
                int   oi = __shfl_xor(besti[pt][r], mask, 64);
                if (ov > best[pt][r] ||
                    (ov == best[pt][r] && oi < besti[pt][r])) {
                    best[pt][r] = ov; besti[pt][r] = oi;
                }
            }
    }
    if (col == 0) {
#pragma unroll
        for (int pt = 0; pt < 2; ++pt)
#pragma unroll
            for (int r = 0; r < 4; ++r) {
                int p = pg * 32 + pt * 16 + g * 4 + r;
                candv[p * 2 + ksel] = best[pt][r];
                candi[p * 2 + ksel] = besti[pt][r];
            }
    }
    __syncthreads();

    // ---- combine the two K-halves, write idx, histogram ----
    if (tid < 64) {
        float v0 = candv[tid * 2],     v1 = candv[tid * 2 + 1];
        int   i0 = candi[tid * 2],     i1 = candi[tid * 2 + 1];
        int bi = (v1 > v0 || (v1 == v0 && i1 < i0)) ? i1 : i0;
        idxs[tid] = bi;
        atomicAdd(&hist[bi], 1.0f);               // exact int counts
        out[(size_t)IDX_OFF + blk * 64 + tid] = (float)bi;
    }
    __syncthreads();

    // ---- epilogue: quantized write (coalesced over w) + loss partial ----
    const int w  = tid & 63;
    const int cq = tid >> 6;                      // channels cq*16..cq*16+15
    const int idx = idxs[w];
    const float* ev = emb + (size_t)idx * 64 + cq * 16;
    const float* zr = zb + w;
    float* outq = out + (size_t)b * 262144 + (size_t)h * 64 + w;
    float lsum = 0.f;
#pragma unroll
    for (int i = 0; i < 4; ++i) {
        float4 qv = *(const float4*)(ev + i * 4);
        float q4[4] = {qv.x, qv.y, qv.z, qv.w};
#pragma unroll
        for (int jj = 0; jj < 4; ++jj) {
            int c = cq * 16 + i * 4 + jj;
            float zv = zr[(size_t)c * 4096];      // L3-hot re-read
            outq[(size_t)c * 4096] = q4[jj];
            float d = q4[jj] - zv;
            lsum = fmaf(d, d, lsum);
        }
    }
#pragma unroll
    for (int off = 32; off > 0; off >>= 1)
        lsum += __shfl_xor(lsum, off, 64);
    if (lane == 0) redw[wv] = lsum;
    __syncthreads();
    if (tid == 0)
        lossp[blk] = redw[0] + redw[1] + redw[2] + redw[3];
}

// ---------------------------------------------------------------------------
// Finalize: loss + perplexity, fixed-order tree. 1 x 1024.
// ---------------------------------------------------------------------------
__global__ void vq_fin(const float* __restrict__ hist,
                       const float* __restrict__ lossp,
                       float* __restrict__ out) {
    __shared__ float sh[1024];
    __shared__ float sl[1024];
    int t = threadIdx.x;
    float hc = hist[t];
    float p  = hc * (1.0f / 65536.0f);
    sh[t] = p * logf(p + 1e-10f);
    sl[t] = lossp[t];
    __syncthreads();
    for (int s = 512; s > 0; s >>= 1) {
        if (t < s) { sh[t] += sh[t + s]; sl[t] += sl[t + s]; }
        __syncthreads();
    }
    if (t == 0) {
        out[LOSS_OFF] = 0.25f * sl[0] / (float)QOUT_SZ;
        out[PERP_OFF] = expf(-sh[0]);
    }
}

extern "C" void kernel_launch(void* const* d_in, const int* in_sizes, int n_in,
                              void* d_out, int out_size, void* d_ws, size_t ws_size,
                              hipStream_t stream) {
    const float* z   = (const float*)d_in[0];   // [16,64,64,64] fp32 NCHW
    const float* emb = (const float*)d_in[1];   // [1024,64] fp32
    float* out = (float*)d_out;
    char*  ws  = (char*)d_ws;

    _Float16* ehi   = (_Float16*)(ws + WS_EHI);
    _Float16* elo   = (_Float16*)(ws + WS_ELO);
    float*    esq   = (float*)(ws + WS_ESQ);
    float*    hist  = (float*)(ws + WS_HIST);
    float*    lossp = (float*)(ws + WS_LOSS);

    vq_pre<<<64, 256, 0, stream>>>(emb, ehi, elo, esq, hist);
    vq_main<<<1024, 256, 0, stream>>>(z, emb, ehi, elo, esq, hist, lossp, out);
    vq_fin<<<1, 1024, 0, stream>>>(hist, lossp, out);
}